// Round 4
// baseline (1640.507 us; speedup 1.0000x reference)
//
#include <hip/hip_runtime.h>
#include <hip/hip_bf16.h>
#include <math.h>

typedef __hip_bfloat16 bf16;

#define B_SZ   16
#define HH     56
#define WW2    56
#define L_TOK  3136
#define C_DIM  192
#define NH_    6
#define DH     32
#define WS_    7
#define SS_    3
#define NW     49           // window tokens
#define NWIN   64           // windows per image (8x8)
#define BWIN   (B_SZ*NWIN)  // 1024
#define TOK    (BWIN*NW)    // 50176
#define HID_   768

__device__ __forceinline__ float b2f(bf16 x){ return __bfloat162float(x); }
__device__ __forceinline__ bf16  f2b(float x){ return __float2bfloat16(x); }

__device__ __forceinline__ float wave_sum64(float v){
    #pragma unroll
    for (int off = 32; off > 0; off >>= 1) v += __shfl_xor(v, off, 64);
    return v;
}

// ---------------------------------------------------------------------------
// Kernel 1: LN1(se), LN1(de), copy(co) + cyclic shift + window partition.
// Inputs fp32, outputs bf16. grid = TOK blocks, 64 threads, 3 ch/thread.
// ---------------------------------------------------------------------------
__global__ void prep_kernel(const float* __restrict__ se, const float* __restrict__ de,
                            const float* __restrict__ co,
                            const float* __restrict__ g1s, const float* __restrict__ b1s,
                            const float* __restrict__ g1d, const float* __restrict__ b1d,
                            bf16* __restrict__ sw, bf16* __restrict__ dw, bf16* __restrict__ cw)
{
    int t   = blockIdx.x;
    int tid = threadIdx.x;
    int b_  = t / NW, n = t % NW;
    int b   = b_ / NWIN, w = b_ % NWIN;
    int wh  = w >> 3, wwi = w & 7;
    int i   = n / WS_, j = n % WS_;
    int hs  = wh*WS_ + i, ws = wwi*WS_ + j;
    int hsrc = hs + SS_; if (hsrc >= HH)  hsrc -= HH;   // roll(-SS)
    int wsrc = ws + SS_; if (wsrc >= WW2) wsrc -= WW2;
    long src = ((long)(b*L_TOK + hsrc*WW2 + wsrc)) * C_DIM;
    long dst = (long)t * C_DIM;

    {
        float x0 = se[src+tid], x1 = se[src+tid+64], x2 = se[src+tid+128];
        float s  = wave_sum64(x0+x1+x2);
        float ss = wave_sum64(x0*x0 + x1*x1 + x2*x2);
        float mean = s * (1.0f/192.0f);
        float var  = ss * (1.0f/192.0f) - mean*mean;
        float rstd = rsqrtf(var + 1e-5f);
        sw[dst+tid]     = f2b((x0-mean)*rstd*g1s[tid]     + b1s[tid]);
        sw[dst+tid+64]  = f2b((x1-mean)*rstd*g1s[tid+64]  + b1s[tid+64]);
        sw[dst+tid+128] = f2b((x2-mean)*rstd*g1s[tid+128] + b1s[tid+128]);
    }
    {
        float x0 = de[src+tid], x1 = de[src+tid+64], x2 = de[src+tid+128];
        float s  = wave_sum64(x0+x1+x2);
        float ss = wave_sum64(x0*x0 + x1*x1 + x2*x2);
        float mean = s * (1.0f/192.0f);
        float var  = ss * (1.0f/192.0f) - mean*mean;
        float rstd = rsqrtf(var + 1e-5f);
        dw[dst+tid]     = f2b((x0-mean)*rstd*g1d[tid]     + b1d[tid]);
        dw[dst+tid+64]  = f2b((x1-mean)*rstd*g1d[tid+64]  + b1d[tid+64]);
        dw[dst+tid+128] = f2b((x2-mean)*rstd*g1d[tid+128] + b1d[tid+128]);
    }
    cw[dst+tid]     = f2b(co[src+tid]);
    cw[dst+tid+64]  = f2b(co[src+tid+64]);
    cw[dst+tid+128] = f2b(co[src+tid+128]);
}

// ---------------------------------------------------------------------------
// Generic tiled GEMM: C[M x Nn] = A[M x K] @ W[K x Nn] + bias, fp32 acc.
// A (bf16) = concat(A1, A2) along K (row stride K1). W/bias fp32.
// MODE 0: plain bf16 out       MODE 1: q/k head-scatter (+scale on q)
// MODE 2: v head-scatter       MODE 3: exact GELU
// MODE 4: recompute resid (fp32 src + bf16 proj via unshift gather) -> fp32 dout
// ---------------------------------------------------------------------------
#define TM 64
#define TN 64
#define KT 16

template<int MODE>
__global__ __launch_bounds__(256)
void gemm_kernel(const bf16* __restrict__ A1, const bf16* __restrict__ A2, int K1, int K,
                 const float* __restrict__ Wt, const float* __restrict__ bias, int Nn,
                 bf16* __restrict__ out, bf16* __restrict__ out2,
                 const float* __restrict__ res_src, const bf16* __restrict__ prj,
                 int t0, float* __restrict__ dout)
{
    __shared__ float As[TM][KT];
    __shared__ float Ws[KT][TN];
    int tid = threadIdx.x;
    int tx = tid & 15, ty = tid >> 4;
    int row0 = blockIdx.x * TM, col0 = blockIdx.y * TN;
    float acc[4][4] = {};

    for (int k0 = 0; k0 < K; k0 += KT) {
        #pragma unroll
        for (int s = 0; s < 4; s++) {
            int e = s*256 + tid;
            int r = e >> 4, kk = e & 15;
            int col = k0 + kk;
            const bf16* src = (col < K1) ? A1 : A2;
            int kc = (col < K1) ? col : col - K1;
            As[r][kk] = b2f(src[(long)(row0+r)*K1 + kc]);
        }
        #pragma unroll
        for (int s = 0; s < 4; s++) {
            int e = s*256 + tid;
            int kk = e >> 6, c = e & 63;
            Ws[kk][c] = Wt[(long)(k0+kk)*Nn + col0 + c];
        }
        __syncthreads();
        #pragma unroll
        for (int kk = 0; kk < KT; kk++) {
            float a[4], wv[4];
            #pragma unroll
            for (int i = 0; i < 4; i++) a[i]  = As[ty*4+i][kk];
            #pragma unroll
            for (int j = 0; j < 4; j++) wv[j] = Ws[kk][tx*4+j];
            #pragma unroll
            for (int i = 0; i < 4; i++)
                #pragma unroll
                for (int j = 0; j < 4; j++)
                    acc[i][j] += a[i]*wv[j];
        }
        __syncthreads();
    }

    #pragma unroll
    for (int i = 0; i < 4; i++) {
        int t = row0 + ty*4 + i;
        if (MODE == 4) {
            // recompute window-reverse + unshift gather for global token tg
            int tg = t0 + t;
            int b = tg / L_TOK, l = tg % L_TOK;
            int h = l / WW2, wcol = l % WW2;
            int hp = h - SS_;    if (hp < 0) hp += HH;
            int wp = wcol - SS_; if (wp < 0) wp += WW2;
            int b_ = b*NWIN + (hp/WS_)*8 + (wp/WS_);
            int n  = (hp%WS_)*WS_ + (wp%WS_);
            long wsoff = ((long)b_*NW + n)*C_DIM;
            long goff  = (long)tg*C_DIM;
            #pragma unroll
            for (int j = 0; j < 4; j++) {
                int oc = col0 + tx*4 + j;
                float v = acc[i][j] + bias[oc];
                dout[goff + oc] = res_src[goff + oc] + b2f(prj[wsoff + oc]) + v;
            }
        } else {
            #pragma unroll
            for (int j = 0; j < 4; j++) {
                int oc = col0 + tx*4 + j;
                float v = acc[i][j] + bias[oc];
                if (MODE == 0) {
                    out[(long)t*Nn + oc] = f2b(v);
                } else if (MODE == 1) {
                    int b_ = t / NW, n = t % NW;
                    if (oc < C_DIM) {
                        int head = oc >> 5, d = oc & 31;
                        out[(((long)b_*NH_ + head)*NW + n)*DH + d] = f2b(v * 0.17677669529663687f);
                    } else {
                        int och = oc - C_DIM;
                        int head = och >> 5, d = och & 31;
                        out2[(((long)b_*NH_ + head)*NW + n)*DH + d] = f2b(v);
                    }
                } else if (MODE == 2) {
                    int b_ = t / NW, n = t % NW;
                    int head = oc >> 5, d = oc & 31;
                    out[(((long)b_*NH_ + head)*NW + n)*DH + d] = f2b(v);
                } else { // MODE 3
                    float g = 0.5f * v * (1.0f + erff(v * 0.70710678118654752f));
                    out[(long)t*Nn + oc] = f2b(g);
                }
            }
        }
    }
}

// ---------------------------------------------------------------------------
// Attention: one block per (window, head), 128 threads.
// ---------------------------------------------------------------------------
__global__ __launch_bounds__(128)
void attn_kernel(const bf16* __restrict__ qb, const bf16* __restrict__ kb,
                 const bf16* __restrict__ vseb, const bf16* __restrict__ vdeb,
                 const float* __restrict__ rpb, const float* __restrict__ maskm,
                 bf16* __restrict__ ose, bf16* __restrict__ ode)
{
    __shared__ float q[NW*DH], k[NW*DH], vs[NW*DH], vd[NW*DH];
    __shared__ float s[NW*50];
    int bh = blockIdx.x;
    int b_ = bh / NH_, head = bh % NH_;
    int w  = b_ & (NWIN-1);
    int tid = threadIdx.x;
    long base = (long)bh * (NW*DH);
    for (int idx = tid; idx < NW*DH; idx += 128) {
        q[idx]  = b2f(qb[base+idx]);
        k[idx]  = b2f(kb[base+idx]);
        vs[idx] = b2f(vseb[base+idx]);
        vd[idx] = b2f(vdeb[base+idx]);
    }
    __syncthreads();
    for (int e = tid; e < NW*NW; e += 128) {
        int row = e / NW, col = e % NW;
        float acc = 0.f;
        #pragma unroll
        for (int d = 0; d < DH; d++) acc += q[row*DH+d]*k[col*DH+d];
        int ri = (row/WS_ - col/WS_ + WS_-1)*(2*WS_-1) + (row%WS_ - col%WS_ + WS_-1);
        acc += rpb[ri*NH_ + head];
        acc += maskm[((long)w*NW + row)*NW + col];
        s[row*50+col] = acc;
    }
    __syncthreads();
    if (tid < NW) {
        int row = tid;
        float mx = -1e30f;
        for (int m2 = 0; m2 < NW; m2++) mx = fmaxf(mx, s[row*50+m2]);
        float sum = 0.f;
        for (int m2 = 0; m2 < NW; m2++) { float e2 = __expf(s[row*50+m2]-mx); s[row*50+m2] = e2; sum += e2; }
        float inv = 1.0f/sum;
        for (int m2 = 0; m2 < NW; m2++) s[row*50+m2] *= inv;
    }
    __syncthreads();
    for (int e = tid; e < NW*DH; e += 128) {
        int row = e / DH, d = e & 31;
        float a1 = 0.f, a2 = 0.f;
        for (int m2 = 0; m2 < NW; m2++) {
            float p = s[row*50+m2];
            a1 += p*vs[m2*DH+d];
            a2 += p*vd[m2*DH+d];
        }
        long o = ((long)b_*NW + row)*C_DIM + head*DH + d;
        ose[o] = f2b(a1);
        ode[o] = f2b(a2);
    }
}

// ---------------------------------------------------------------------------
// Fused window-reverse + un-shift + residual (fp32, on the fly) + LN2.
// Emits ONLY the LN2-normalized bf16 (MLP input); trunk recomputed later.
// grid = TOK, 64 threads.
// ---------------------------------------------------------------------------
__global__ void resid_ln2_kernel(const float* __restrict__ se, const float* __restrict__ de,
                                 const bf16* __restrict__ pse, const bf16* __restrict__ pde,
                                 const float* __restrict__ g2s, const float* __restrict__ bb2s,
                                 const float* __restrict__ g2d, const float* __restrict__ bb2d,
                                 bf16* __restrict__ xns, bf16* __restrict__ xnd)
{
    int t = blockIdx.x, tid = threadIdx.x;
    int b = t / L_TOK, l = t % L_TOK;
    int h = l / WW2, wc = l % WW2;
    int hp = h - SS_;  if (hp < 0) hp += HH;
    int wp = wc - SS_; if (wp < 0) wp += WW2;
    int b_ = b*NWIN + (hp/WS_)*8 + (wp/WS_);
    int n  = (hp%WS_)*WS_ + (wp%WS_);
    long wsoff = ((long)b_*NW + n)*C_DIM;
    long off   = (long)t*C_DIM;
    {
        float x0 = se[off+tid]     + b2f(pse[wsoff+tid]);
        float x1 = se[off+tid+64]  + b2f(pse[wsoff+tid+64]);
        float x2 = se[off+tid+128] + b2f(pse[wsoff+tid+128]);
        float s  = wave_sum64(x0+x1+x2);
        float ss = wave_sum64(x0*x0 + x1*x1 + x2*x2);
        float mean = s * (1.0f/192.0f);
        float var  = ss * (1.0f/192.0f) - mean*mean;
        float rstd = rsqrtf(var + 1e-5f);
        xns[off+tid]     = f2b((x0-mean)*rstd*g2s[tid]     + bb2s[tid]);
        xns[off+tid+64]  = f2b((x1-mean)*rstd*g2s[tid+64]  + bb2s[tid+64]);
        xns[off+tid+128] = f2b((x2-mean)*rstd*g2s[tid+128] + bb2s[tid+128]);
    }
    {
        float x0 = de[off+tid]     + b2f(pde[wsoff+tid]);
        float x1 = de[off+tid+64]  + b2f(pde[wsoff+tid+64]);
        float x2 = de[off+tid+128] + b2f(pde[wsoff+tid+128]);
        float s  = wave_sum64(x0+x1+x2);
        float ss = wave_sum64(x0*x0 + x1*x1 + x2*x2);
        float mean = s * (1.0f/192.0f);
        float var  = ss * (1.0f/192.0f) - mean*mean;
        float rstd = rsqrtf(var + 1e-5f);
        xnd[off+tid]     = f2b((x0-mean)*rstd*g2d[tid]     + bb2d[tid]);
        xnd[off+tid+64]  = f2b((x1-mean)*rstd*g2d[tid+64]  + bb2d[tid+64]);
        xnd[off+tid+128] = f2b((x2-mean)*rstd*g2d[tid+128] + bb2d[tid+128]);
    }
}

// ---------------------------------------------------------------------------
extern "C" void kernel_launch(void* const* d_in, const int* in_sizes, int n_in,
                              void* d_out, int out_size, void* d_ws, size_t ws_size,
                              hipStream_t stream)
{
    const float* se     = (const float*)d_in[0];
    const float* de     = (const float*)d_in[1];
    const float* co     = (const float*)d_in[2];
    const float* maskm  = (const float*)d_in[3];
    const float* n1se_g = (const float*)d_in[4];
    const float* n1se_b = (const float*)d_in[5];
    const float* n1de_g = (const float*)d_in[6];
    const float* n1de_b = (const float*)d_in[7];
    const float* rpb    = (const float*)d_in[8];
    const float* vse_w  = (const float*)d_in[9];
    const float* vse_b  = (const float*)d_in[10];
    const float* vde_w  = (const float*)d_in[11];
    const float* vde_b  = (const float*)d_in[12];
    const float* qk_w   = (const float*)d_in[13];
    const float* qk_b   = (const float*)d_in[14];
    const float* pse_w  = (const float*)d_in[15];
    const float* pse_b  = (const float*)d_in[16];
    const float* pde_w  = (const float*)d_in[17];
    const float* pde_b  = (const float*)d_in[18];
    const float* n2se_g = (const float*)d_in[19];
    const float* n2se_b = (const float*)d_in[20];
    const float* n2de_g = (const float*)d_in[21];
    const float* n2de_b = (const float*)d_in[22];
    const float* mse_w1 = (const float*)d_in[23];
    const float* mse_b1 = (const float*)d_in[24];
    const float* mse_w2 = (const float*)d_in[25];
    const float* mse_b2 = (const float*)d_in[26];
    const float* mde_w1 = (const float*)d_in[27];
    const float* mde_b1 = (const float*)d_in[28];
    const float* mde_w2 = (const float*)d_in[29];
    const float* mde_b2 = (const float*)d_in[30];

    // ---- workspace: 6 bf16 planes of U = TOK*C*2 bytes (~110 MB total) ----
    //  s0: sw  -> qb  -> pse            s1: dw  -> kb  -> pde
    //  s2: cw  -> ose -> xns            s3: vse -> xnd
    //  s4: vde -> hid(lo)               s5: ode -> hid(hi)
    char* ws = (char*)d_ws;
    const size_t U = (size_t)TOK * C_DIM * 2;   // 19,267,584 bytes
    bf16* sw  = (bf16*)(ws + 0*U);
    bf16* dw  = (bf16*)(ws + 1*U);
    bf16* cw  = (bf16*)(ws + 2*U);
    bf16* vse = (bf16*)(ws + 3*U);
    bf16* vde = (bf16*)(ws + 4*U);
    bf16* ode = (bf16*)(ws + 5*U);
    bf16* qb  = (bf16*)(ws + 0*U);   // after sw dead
    bf16* kb  = (bf16*)(ws + 1*U);   // after dw dead
    bf16* ose = (bf16*)(ws + 2*U);   // after cw dead
    bf16* pse = (bf16*)(ws + 0*U);   // after qb dead
    bf16* pde = (bf16*)(ws + 1*U);   // after kb dead
    bf16* xns = (bf16*)(ws + 2*U);   // after ose dead
    bf16* xnd = (bf16*)(ws + 3*U);   // after vse dead
    bf16* hid = (bf16*)(ws + 4*U);   // 2 planes (chunked MLP), after vde/ode dead

    float* dout = (float*)d_out;     // fp32 output (reference returns float32)
    dim3 blk(256);

    // 1. LN1 + shift + partition
    prep_kernel<<<TOK, 64, 0, stream>>>(se, de, co, n1se_g, n1se_b, n1de_g, n1de_b, sw, dw, cw);
    // 2. v_se = [sw|cw]@vse_w ; v_de = [dw|cw]@vde_w
    gemm_kernel<2><<<dim3(TOK/TM, C_DIM/TN), blk, 0, stream>>>(sw, cw, C_DIM, 2*C_DIM, vse_w, vse_b, C_DIM,
                                                               vse, nullptr, nullptr, nullptr, 0, nullptr);
    gemm_kernel<2><<<dim3(TOK/TM, C_DIM/TN), blk, 0, stream>>>(dw, cw, C_DIM, 2*C_DIM, vde_w, vde_b, C_DIM,
                                                               vde, nullptr, nullptr, nullptr, 0, nullptr);
    // 3. qk = cw @ qk_w   (writes qb over sw, kb over dw)
    gemm_kernel<1><<<dim3(TOK/TM, 384/TN), blk, 0, stream>>>(cw, cw, C_DIM, C_DIM, qk_w, qk_b, 384,
                                                             qb, kb, nullptr, nullptr, 0, nullptr);
    // 4. attention (both streams)
    attn_kernel<<<BWIN*NH_, 128, 0, stream>>>(qb, kb, vse, vde, rpb, maskm, ose, ode);
    // 5. output projections
    gemm_kernel<0><<<dim3(TOK/TM, C_DIM/TN), blk, 0, stream>>>(ose, ose, C_DIM, C_DIM, pse_w, pse_b, C_DIM,
                                                               pse, nullptr, nullptr, nullptr, 0, nullptr);
    gemm_kernel<0><<<dim3(TOK/TM, C_DIM/TN), blk, 0, stream>>>(ode, ode, C_DIM, C_DIM, pde_w, pde_b, C_DIM,
                                                               pde, nullptr, nullptr, nullptr, 0, nullptr);
    // 6. fused reverse+unshift+residual+LN2 (xn only; trunk recomputed in MODE 4)
    resid_ln2_kernel<<<TOK, 64, 0, stream>>>(se, de, pse, pde,
                                             n2se_g, n2se_b, n2de_g, n2de_b, xns, xnd);
    // 7. MLPs in 2 token-chunks so hid fits in 2 planes
    const int CH = TOK/2;   // 25088
    for (int c0 = 0; c0 < 2; c0++) {
        int t0 = c0 * CH;
        gemm_kernel<3><<<dim3(CH/TM, HID_/TN), blk, 0, stream>>>(xns + (long)t0*C_DIM, xns + (long)t0*C_DIM,
                                                                 C_DIM, C_DIM, mse_w1, mse_b1, HID_,
                                                                 hid, nullptr, nullptr, nullptr, 0, nullptr);
        gemm_kernel<4><<<dim3(CH/TM, C_DIM/TN), blk, 0, stream>>>(hid, hid, HID_, HID_, mse_w2, mse_b2, C_DIM,
                                                                  nullptr, nullptr, se, pse, t0, dout);
    }
    for (int c0 = 0; c0 < 2; c0++) {
        int t0 = c0 * CH;
        gemm_kernel<3><<<dim3(CH/TM, HID_/TN), blk, 0, stream>>>(xnd + (long)t0*C_DIM, xnd + (long)t0*C_DIM,
                                                                 C_DIM, C_DIM, mde_w1, mde_b1, HID_,
                                                                 hid, nullptr, nullptr, nullptr, 0, nullptr);
        gemm_kernel<4><<<dim3(CH/TM, C_DIM/TN), blk, 0, stream>>>(hid, hid, HID_, HID_, mde_w2, mde_b2, C_DIM,
                                                                  nullptr, nullptr, de, pde, t0,
                                                                  dout + (size_t)TOK*C_DIM);
    }
}

// Round 5
// 533.890 us; speedup vs baseline: 3.0727x; 3.0727x over previous
//
#include <hip/hip_runtime.h>
#include <hip/hip_bf16.h>
#include <math.h>

typedef __hip_bfloat16 bf16;
typedef __attribute__((ext_vector_type(8))) short short8;
typedef __attribute__((ext_vector_type(4))) float f32x4;

#define B_SZ   16
#define HH     56
#define WW2    56
#define L_TOK  3136
#define C_DIM  192
#define NH_    6
#define DH     32
#define WS_    7
#define SS_    3
#define NW     49           // window tokens
#define NWIN   64           // windows per image (8x8)
#define BWIN   (B_SZ*NWIN)  // 1024
#define TOK    (BWIN*NW)    // 50176
#define HID_   768

__device__ __forceinline__ float b2f(bf16 x){ return __bfloat162float(x); }
__device__ __forceinline__ bf16  f2b(float x){ return __float2bfloat16(x); }
__device__ __forceinline__ short f2bs(float x){ bf16 h = __float2bfloat16(x); return *reinterpret_cast<short*>(&h); }

__device__ __forceinline__ float wave_sum64(float v){
    #pragma unroll
    for (int off = 32; off > 0; off >>= 1) v += __shfl_xor(v, off, 64);
    return v;
}

// ---------------------------------------------------------------------------
// Kernel 1: LN1(se), LN1(de), copy(co) + cyclic shift + window partition.
// ---------------------------------------------------------------------------
__global__ void prep_kernel(const float* __restrict__ se, const float* __restrict__ de,
                            const float* __restrict__ co,
                            const float* __restrict__ g1s, const float* __restrict__ b1s,
                            const float* __restrict__ g1d, const float* __restrict__ b1d,
                            bf16* __restrict__ sw, bf16* __restrict__ dw, bf16* __restrict__ cw)
{
    int t   = blockIdx.x;
    int tid = threadIdx.x;
    int b_  = t / NW, n = t % NW;
    int b   = b_ / NWIN, w = b_ % NWIN;
    int wh  = w >> 3, wwi = w & 7;
    int i   = n / WS_, j = n % WS_;
    int hs  = wh*WS_ + i, ws = wwi*WS_ + j;
    int hsrc = hs + SS_; if (hsrc >= HH)  hsrc -= HH;
    int wsrc = ws + SS_; if (wsrc >= WW2) wsrc -= WW2;
    long src = ((long)(b*L_TOK + hsrc*WW2 + wsrc)) * C_DIM;
    long dst = (long)t * C_DIM;

    {
        float x0 = se[src+tid], x1 = se[src+tid+64], x2 = se[src+tid+128];
        float s  = wave_sum64(x0+x1+x2);
        float ss = wave_sum64(x0*x0 + x1*x1 + x2*x2);
        float mean = s * (1.0f/192.0f);
        float var  = ss * (1.0f/192.0f) - mean*mean;
        float rstd = rsqrtf(var + 1e-5f);
        sw[dst+tid]     = f2b((x0-mean)*rstd*g1s[tid]     + b1s[tid]);
        sw[dst+tid+64]  = f2b((x1-mean)*rstd*g1s[tid+64]  + b1s[tid+64]);
        sw[dst+tid+128] = f2b((x2-mean)*rstd*g1s[tid+128] + b1s[tid+128]);
    }
    {
        float x0 = de[src+tid], x1 = de[src+tid+64], x2 = de[src+tid+128];
        float s  = wave_sum64(x0+x1+x2);
        float ss = wave_sum64(x0*x0 + x1*x1 + x2*x2);
        float mean = s * (1.0f/192.0f);
        float var  = ss * (1.0f/192.0f) - mean*mean;
        float rstd = rsqrtf(var + 1e-5f);
        dw[dst+tid]     = f2b((x0-mean)*rstd*g1d[tid]     + b1d[tid]);
        dw[dst+tid+64]  = f2b((x1-mean)*rstd*g1d[tid+64]  + b1d[tid+64]);
        dw[dst+tid+128] = f2b((x2-mean)*rstd*g1d[tid+128] + b1d[tid+128]);
    }
    cw[dst+tid]     = f2b(co[src+tid]);
    cw[dst+tid+64]  = f2b(co[src+tid+64]);
    cw[dst+tid+128] = f2b(co[src+tid+128]);
}

// ---------------------------------------------------------------------------
// MFMA GEMM: C[M x Nn] = A[M x K](bf16) @ W[K x Nn](fp32->bf16) + bias(fp32)
// tile 128x64, 4 waves (2x2), each wave 64x32 via mfma_f32_16x16x32_bf16.
// LDS is fragment-ordered => all ds_read_b128 lane-linear (conflict-free).
// MODE 0: plain bf16 out       MODE 1: q/k head-scatter (+scale on q)
// MODE 2: v head-scatter       MODE 3: exact GELU
// MODE 4: resid (fp32 src + bf16 proj via unshift gather) -> fp32 dout
// ---------------------------------------------------------------------------
#define BM 128
#define BN 64
#define BK 32

template<int MODE>
__global__ __launch_bounds__(256)
void mgemm(const bf16* __restrict__ A1, const bf16* __restrict__ A2, int K1, int K,
           const float* __restrict__ W, const float* __restrict__ bias, int Nn,
           bf16* __restrict__ out, bf16* __restrict__ out2,
           const float* __restrict__ res_src, const bf16* __restrict__ prj,
           int t0, float* __restrict__ dout)
{
    __shared__ short AsF[8][64][8];   // [m-tile][lane][j]  8 KB
    __shared__ short BsF[4][64][8];   // [n-tile][lane][j]  4 KB
    int tid  = threadIdx.x;
    int wid  = tid >> 6, lane = tid & 63;
    int wr   = wid >> 1, wc = wid & 1;
    int row0 = blockIdx.x * BM, col0 = blockIdx.y * BN;

    f32x4 acc[4][2];
    #pragma unroll
    for (int m = 0; m < 4; m++)
        #pragma unroll
        for (int n = 0; n < 2; n++)
            acc[m][n] = (f32x4){0.f, 0.f, 0.f, 0.f};

    int ar = tid >> 2, akseg = tid & 3;      // A: row ar/ar+64, k-seg akseg*8
    int bc = tid & 63, bk8 = tid >> 6;       // B: col bc, k = bk8*8 + j

    for (int k0 = 0; k0 < K; k0 += BK) {
        // ---- stage A (frag-ordered; 16B vector loads + conflict-free b128 writes)
        {
            int col = k0 + akseg*8;
            const bf16* asrc = (col < K1) ? A1 : A2;
            int akc = (col < K1) ? col : col - K1;
            #pragma unroll
            for (int rr = 0; rr < 2; rr++) {
                int r = ar + rr*64;
                short8 av = *(const short8*)(asrc + (long)(row0 + r)*K1 + akc);
                *((short8*)&AsF[r >> 4][(r & 15) + (akseg << 4)][0]) = av;
            }
        }
        // ---- stage B (fp32 coalesced loads, cvt to bf16, frag-ordered write)
        {
            short8 bv;
            #pragma unroll
            for (int j = 0; j < 8; j++)
                bv[j] = f2bs(W[(long)(k0 + bk8*8 + j)*Nn + col0 + bc]);
            *((short8*)&BsF[bc >> 4][(bc & 15) + (bk8 << 4)][0]) = bv;
        }
        __syncthreads();
        short8 af[4], bfr[2];
        #pragma unroll
        for (int m = 0; m < 4; m++) af[m]  = *((short8*)&AsF[wr*4 + m][lane][0]);
        #pragma unroll
        for (int n = 0; n < 2; n++) bfr[n] = *((short8*)&BsF[wc*2 + n][lane][0]);
        #pragma unroll
        for (int m = 0; m < 4; m++)
            #pragma unroll
            for (int n = 0; n < 2; n++)
                acc[m][n] = __builtin_amdgcn_mfma_f32_16x16x32_bf16(af[m], bfr[n], acc[m][n], 0, 0, 0);
        __syncthreads();
    }

    // ---- epilogue: D row = 4*(lane>>4)+reg, col = lane&15
    #pragma unroll
    for (int m = 0; m < 4; m++) {
        #pragma unroll
        for (int rr = 0; rr < 4; rr++) {
            int t = row0 + wr*64 + m*16 + (lane >> 4)*4 + rr;
            if (MODE == 4) {
                int tg = t0 + t;
                int b = tg / L_TOK, l = tg % L_TOK;
                int h = l / WW2, wcol = l % WW2;
                int hp = h - SS_;    if (hp < 0) hp += HH;
                int wp = wcol - SS_; if (wp < 0) wp += WW2;
                int b_ = b*NWIN + (hp/WS_)*8 + (wp/WS_);
                int n  = (hp%WS_)*WS_ + (wp%WS_);
                long wsoff = ((long)b_*NW + n)*C_DIM;
                long goff  = (long)tg*C_DIM;
                #pragma unroll
                for (int n2 = 0; n2 < 2; n2++) {
                    int oc = col0 + wc*32 + n2*16 + (lane & 15);
                    float v = acc[m][n2][rr] + bias[oc];
                    dout[goff + oc] = res_src[goff + oc] + b2f(prj[wsoff + oc]) + v;
                }
            } else {
                #pragma unroll
                for (int n2 = 0; n2 < 2; n2++) {
                    int oc = col0 + wc*32 + n2*16 + (lane & 15);
                    float v = acc[m][n2][rr] + bias[oc];
                    if (MODE == 0) {
                        out[(long)t*Nn + oc] = f2b(v);
                    } else if (MODE == 1) {
                        int b_ = t / NW, n = t % NW;
                        if (oc < C_DIM) {
                            int head = oc >> 5, d = oc & 31;
                            out[(((long)b_*NH_ + head)*NW + n)*DH + d] = f2b(v * 0.17677669529663687f);
                        } else {
                            int och = oc - C_DIM;
                            int head = och >> 5, d = och & 31;
                            out2[(((long)b_*NH_ + head)*NW + n)*DH + d] = f2b(v);
                        }
                    } else if (MODE == 2) {
                        int b_ = t / NW, n = t % NW;
                        int head = oc >> 5, d = oc & 31;
                        out[(((long)b_*NH_ + head)*NW + n)*DH + d] = f2b(v);
                    } else { // MODE 3
                        float g = 0.5f * v * (1.0f + erff(v * 0.70710678118654752f));
                        out[(long)t*Nn + oc] = f2b(g);
                    }
                }
            }
        }
    }
}

// ---------------------------------------------------------------------------
// Attention: one block per (window, head), 128 threads. K stored transposed
// with odd stride 57 -> conflict-free QK^T reads (was 32-way on bank d).
// ---------------------------------------------------------------------------
#define KTS 57

__global__ __launch_bounds__(128)
void attn_kernel(const bf16* __restrict__ qb, const bf16* __restrict__ kb,
                 const bf16* __restrict__ vseb, const bf16* __restrict__ vdeb,
                 const float* __restrict__ rpb, const float* __restrict__ maskm,
                 bf16* __restrict__ ose, bf16* __restrict__ ode)
{
    __shared__ float q[NW*DH], kT[DH*KTS], vs[NW*DH], vd[NW*DH];
    __shared__ float s[NW*50];
    int bh = blockIdx.x;
    int b_ = bh / NH_, head = bh % NH_;
    int w  = b_ & (NWIN-1);
    int tid = threadIdx.x;
    long base = (long)bh * (NW*DH);
    for (int idx = tid; idx < NW*DH; idx += 128) {
        q[idx]  = b2f(qb[base+idx]);
        kT[(idx & 31)*KTS + (idx >> 5)] = b2f(kb[base+idx]);
        vs[idx] = b2f(vseb[base+idx]);
        vd[idx] = b2f(vdeb[base+idx]);
    }
    __syncthreads();
    for (int e = tid; e < NW*NW; e += 128) {
        int row = e / NW, col = e % NW;
        float acc = 0.f;
        #pragma unroll
        for (int d = 0; d < DH; d++) acc += q[row*DH+d]*kT[d*KTS+col];
        int ri = (row/WS_ - col/WS_ + WS_-1)*(2*WS_-1) + (row%WS_ - col%WS_ + WS_-1);
        acc += rpb[ri*NH_ + head];
        acc += maskm[((long)w*NW + row)*NW + col];
        s[row*50+col] = acc;
    }
    __syncthreads();
    if (tid < NW) {
        int row = tid;
        float mx = -1e30f;
        for (int m2 = 0; m2 < NW; m2++) mx = fmaxf(mx, s[row*50+m2]);
        float sum = 0.f;
        for (int m2 = 0; m2 < NW; m2++) { float e2 = __expf(s[row*50+m2]-mx); s[row*50+m2] = e2; sum += e2; }
        float inv = 1.0f/sum;
        for (int m2 = 0; m2 < NW; m2++) s[row*50+m2] *= inv;
    }
    __syncthreads();
    for (int e = tid; e < NW*DH; e += 128) {
        int row = e / DH, d = e & 31;
        float a1 = 0.f, a2 = 0.f;
        for (int m2 = 0; m2 < NW; m2++) {
            float p = s[row*50+m2];
            a1 += p*vs[m2*DH+d];
            a2 += p*vd[m2*DH+d];
        }
        long o = ((long)b_*NW + row)*C_DIM + head*DH + d;
        ose[o] = f2b(a1);
        ode[o] = f2b(a2);
    }
}

// ---------------------------------------------------------------------------
// Fused window-reverse + un-shift + residual (fp32 on the fly) + LN2.
// ---------------------------------------------------------------------------
__global__ void resid_ln2_kernel(const float* __restrict__ se, const float* __restrict__ de,
                                 const bf16* __restrict__ pse, const bf16* __restrict__ pde,
                                 const float* __restrict__ g2s, const float* __restrict__ bb2s,
                                 const float* __restrict__ g2d, const float* __restrict__ bb2d,
                                 bf16* __restrict__ xns, bf16* __restrict__ xnd)
{
    int t = blockIdx.x, tid = threadIdx.x;
    int b = t / L_TOK, l = t % L_TOK;
    int h = l / WW2, wc = l % WW2;
    int hp = h - SS_;  if (hp < 0) hp += HH;
    int wp = wc - SS_; if (wp < 0) wp += WW2;
    int b_ = b*NWIN + (hp/WS_)*8 + (wp/WS_);
    int n  = (hp%WS_)*WS_ + (wp%WS_);
    long wsoff = ((long)b_*NW + n)*C_DIM;
    long off   = (long)t*C_DIM;
    {
        float x0 = se[off+tid]     + b2f(pse[wsoff+tid]);
        float x1 = se[off+tid+64]  + b2f(pse[wsoff+tid+64]);
        float x2 = se[off+tid+128] + b2f(pse[wsoff+tid+128]);
        float s  = wave_sum64(x0+x1+x2);
        float ss = wave_sum64(x0*x0 + x1*x1 + x2*x2);
        float mean = s * (1.0f/192.0f);
        float var  = ss * (1.0f/192.0f) - mean*mean;
        float rstd = rsqrtf(var + 1e-5f);
        xns[off+tid]     = f2b((x0-mean)*rstd*g2s[tid]     + bb2s[tid]);
        xns[off+tid+64]  = f2b((x1-mean)*rstd*g2s[tid+64]  + bb2s[tid+64]);
        xns[off+tid+128] = f2b((x2-mean)*rstd*g2s[tid+128] + bb2s[tid+128]);
    }
    {
        float x0 = de[off+tid]     + b2f(pde[wsoff+tid]);
        float x1 = de[off+tid+64]  + b2f(pde[wsoff+tid+64]);
        float x2 = de[off+tid+128] + b2f(pde[wsoff+tid+128]);
        float s  = wave_sum64(x0+x1+x2);
        float ss = wave_sum64(x0*x0 + x1*x1 + x2*x2);
        float mean = s * (1.0f/192.0f);
        float var  = ss * (1.0f/192.0f) - mean*mean;
        float rstd = rsqrtf(var + 1e-5f);
        xnd[off+tid]     = f2b((x0-mean)*rstd*g2d[tid]     + bb2d[tid]);
        xnd[off+tid+64]  = f2b((x1-mean)*rstd*g2d[tid+64]  + bb2d[tid+64]);
        xnd[off+tid+128] = f2b((x2-mean)*rstd*g2d[tid+128] + bb2d[tid+128]);
    }
}

// ---------------------------------------------------------------------------
extern "C" void kernel_launch(void* const* d_in, const int* in_sizes, int n_in,
                              void* d_out, int out_size, void* d_ws, size_t ws_size,
                              hipStream_t stream)
{
    const float* se     = (const float*)d_in[0];
    const float* de     = (const float*)d_in[1];
    const float* co     = (const float*)d_in[2];
    const float* maskm  = (const float*)d_in[3];
    const float* n1se_g = (const float*)d_in[4];
    const float* n1se_b = (const float*)d_in[5];
    const float* n1de_g = (const float*)d_in[6];
    const float* n1de_b = (const float*)d_in[7];
    const float* rpb    = (const float*)d_in[8];
    const float* vse_w  = (const float*)d_in[9];
    const float* vse_b  = (const float*)d_in[10];
    const float* vde_w  = (const float*)d_in[11];
    const float* vde_b  = (const float*)d_in[12];
    const float* qk_w   = (const float*)d_in[13];
    const float* qk_b   = (const float*)d_in[14];
    const float* pse_w  = (const float*)d_in[15];
    const float* pse_b  = (const float*)d_in[16];
    const float* pde_w  = (const float*)d_in[17];
    const float* pde_b  = (const float*)d_in[18];
    const float* n2se_g = (const float*)d_in[19];
    const float* n2se_b = (const float*)d_in[20];
    const float* n2de_g = (const float*)d_in[21];
    const float* n2de_b = (const float*)d_in[22];
    const float* mse_w1 = (const float*)d_in[23];
    const float* mse_b1 = (const float*)d_in[24];
    const float* mse_w2 = (const float*)d_in[25];
    const float* mse_b2 = (const float*)d_in[26];
    const float* mde_w1 = (const float*)d_in[27];
    const float* mde_b1 = (const float*)d_in[28];
    const float* mde_w2 = (const float*)d_in[29];
    const float* mde_b2 = (const float*)d_in[30];

    // ---- workspace: 6 bf16 planes of U = TOK*C*2 bytes (~110 MB total) ----
    //  s0: sw  -> qb  -> pse            s1: dw  -> kb  -> pde
    //  s2: cw  -> ose -> xns            s3: vse -> xnd
    //  s4: vde -> hid(lo)               s5: ode -> hid(hi)
    char* ws = (char*)d_ws;
    const size_t U = (size_t)TOK * C_DIM * 2;   // 19,267,584 bytes
    bf16* sw  = (bf16*)(ws + 0*U);
    bf16* dw  = (bf16*)(ws + 1*U);
    bf16* cw  = (bf16*)(ws + 2*U);
    bf16* vse = (bf16*)(ws + 3*U);
    bf16* vde = (bf16*)(ws + 4*U);
    bf16* ode = (bf16*)(ws + 5*U);
    bf16* qb  = (bf16*)(ws + 0*U);
    bf16* kb  = (bf16*)(ws + 1*U);
    bf16* ose = (bf16*)(ws + 2*U);
    bf16* pse = (bf16*)(ws + 0*U);
    bf16* pde = (bf16*)(ws + 1*U);
    bf16* xns = (bf16*)(ws + 2*U);
    bf16* xnd = (bf16*)(ws + 3*U);
    bf16* hid = (bf16*)(ws + 4*U);   // 2 planes (chunked MLP)

    float* dout = (float*)d_out;     // fp32 output
    dim3 blk(256);

    // 1. LN1 + shift + partition
    prep_kernel<<<TOK, 64, 0, stream>>>(se, de, co, n1se_g, n1se_b, n1de_g, n1de_b, sw, dw, cw);
    // 2. v_se = [sw|cw]@vse_w ; v_de = [dw|cw]@vde_w
    mgemm<2><<<dim3(TOK/BM, C_DIM/BN), blk, 0, stream>>>(sw, cw, C_DIM, 2*C_DIM, vse_w, vse_b, C_DIM,
                                                         vse, nullptr, nullptr, nullptr, 0, nullptr);
    mgemm<2><<<dim3(TOK/BM, C_DIM/BN), blk, 0, stream>>>(dw, cw, C_DIM, 2*C_DIM, vde_w, vde_b, C_DIM,
                                                         vde, nullptr, nullptr, nullptr, 0, nullptr);
    // 3. qk = cw @ qk_w   (writes qb over sw, kb over dw)
    mgemm<1><<<dim3(TOK/BM, 384/BN), blk, 0, stream>>>(cw, cw, C_DIM, C_DIM, qk_w, qk_b, 384,
                                                       qb, kb, nullptr, nullptr, 0, nullptr);
    // 4. attention (both streams)
    attn_kernel<<<BWIN*NH_, 128, 0, stream>>>(qb, kb, vse, vde, rpb, maskm, ose, ode);
    // 5. output projections
    mgemm<0><<<dim3(TOK/BM, C_DIM/BN), blk, 0, stream>>>(ose, ose, C_DIM, C_DIM, pse_w, pse_b, C_DIM,
                                                         pse, nullptr, nullptr, nullptr, 0, nullptr);
    mgemm<0><<<dim3(TOK/BM, C_DIM/BN), blk, 0, stream>>>(ode, ode, C_DIM, C_DIM, pde_w, pde_b, C_DIM,
                                                         pde, nullptr, nullptr, nullptr, 0, nullptr);
    // 6. fused reverse+unshift+residual+LN2 (xn only; trunk recomputed in MODE 4)
    resid_ln2_kernel<<<TOK, 64, 0, stream>>>(se, de, pse, pde,
                                             n2se_g, n2se_b, n2de_g, n2de_b, xns, xnd);
    // 7. MLPs in 2 token-chunks so hid fits in 2 planes
    const int CH = TOK/2;   // 25088
    for (int c0 = 0; c0 < 2; c0++) {
        int t0 = c0 * CH;
        mgemm<3><<<dim3(CH/BM, HID_/BN), blk, 0, stream>>>(xns + (long)t0*C_DIM, xns + (long)t0*C_DIM,
                                                           C_DIM, C_DIM, mse_w1, mse_b1, HID_,
                                                           hid, nullptr, nullptr, nullptr, 0, nullptr);
        mgemm<4><<<dim3(CH/BM, C_DIM/BN), blk, 0, stream>>>(hid, hid, HID_, HID_, mse_w2, mse_b2, C_DIM,
                                                            nullptr, nullptr, se, pse, t0, dout);
    }
    for (int c0 = 0; c0 < 2; c0++) {
        int t0 = c0 * CH;
        mgemm<3><<<dim3(CH/BM, HID_/BN), blk, 0, stream>>>(xnd + (long)t0*C_DIM, xnd + (long)t0*C_DIM,
                                                           C_DIM, C_DIM, mde_w1, mde_b1, HID_,
                                                           hid, nullptr, nullptr, nullptr, 0, nullptr);
        mgemm<4><<<dim3(CH/BM, C_DIM/BN), blk, 0, stream>>>(hid, hid, HID_, HID_, mde_w2, mde_b2, C_DIM,
                                                            nullptr, nullptr, de, pde, t0,
                                                            dout + (size_t)TOK*C_DIM);
    }
}

// Round 6
// 447.538 us; speedup vs baseline: 3.6656x; 1.1929x over previous
//
#include <hip/hip_runtime.h>
#include <hip/hip_bf16.h>
#include <math.h>

typedef __hip_bfloat16 bf16;
typedef __attribute__((ext_vector_type(8))) short short8;
typedef __attribute__((ext_vector_type(4))) float f32x4;

#define B_SZ   16
#define HH     56
#define WW2    56
#define L_TOK  3136
#define C_DIM  192
#define NH_    6
#define DH     32
#define WS_    7
#define SS_    3
#define NW     49
#define NWIN   64
#define BWIN   (B_SZ*NWIN)  // 1024
#define TOK    (BWIN*NW)    // 50176
#define HID_   768

__device__ __forceinline__ float b2f(bf16 x){ return __bfloat162float(x); }
__device__ __forceinline__ bf16  f2b(float x){ return __float2bfloat16(x); }
__device__ __forceinline__ short f2bs(float x){ bf16 h = __float2bfloat16(x); return *reinterpret_cast<short*>(&h); }

__device__ __forceinline__ float wave_sum64(float v){
    #pragma unroll
    for (int off = 32; off > 0; off >>= 1) v += __shfl_xor(v, off, 64);
    return v;
}

// ---------------------------------------------------------------------------
// LN1(se), LN1(de), copy(co) + cyclic shift + window partition.
// ---------------------------------------------------------------------------
__global__ void prep_kernel(const float* __restrict__ se, const float* __restrict__ de,
                            const float* __restrict__ co,
                            const float* __restrict__ g1s, const float* __restrict__ b1s,
                            const float* __restrict__ g1d, const float* __restrict__ b1d,
                            bf16* __restrict__ sw, bf16* __restrict__ dw, bf16* __restrict__ cw)
{
    int t   = blockIdx.x;
    int tid = threadIdx.x;
    int b_  = t / NW, n = t % NW;
    int b   = b_ / NWIN, w = b_ % NWIN;
    int wh  = w >> 3, wwi = w & 7;
    int i   = n / WS_, j = n % WS_;
    int hs  = wh*WS_ + i, ws = wwi*WS_ + j;
    int hsrc = hs + SS_; if (hsrc >= HH)  hsrc -= HH;
    int wsrc = ws + SS_; if (wsrc >= WW2) wsrc -= WW2;
    long src = ((long)(b*L_TOK + hsrc*WW2 + wsrc)) * C_DIM;
    long dst = (long)t * C_DIM;

    {
        float x0 = se[src+tid], x1 = se[src+tid+64], x2 = se[src+tid+128];
        float s  = wave_sum64(x0+x1+x2);
        float ss = wave_sum64(x0*x0 + x1*x1 + x2*x2);
        float mean = s * (1.0f/192.0f);
        float var  = ss * (1.0f/192.0f) - mean*mean;
        float rstd = rsqrtf(var + 1e-5f);
        sw[dst+tid]     = f2b((x0-mean)*rstd*g1s[tid]     + b1s[tid]);
        sw[dst+tid+64]  = f2b((x1-mean)*rstd*g1s[tid+64]  + b1s[tid+64]);
        sw[dst+tid+128] = f2b((x2-mean)*rstd*g1s[tid+128] + b1s[tid+128]);
    }
    {
        float x0 = de[src+tid], x1 = de[src+tid+64], x2 = de[src+tid+128];
        float s  = wave_sum64(x0+x1+x2);
        float ss = wave_sum64(x0*x0 + x1*x1 + x2*x2);
        float mean = s * (1.0f/192.0f);
        float var  = ss * (1.0f/192.0f) - mean*mean;
        float rstd = rsqrtf(var + 1e-5f);
        dw[dst+tid]     = f2b((x0-mean)*rstd*g1d[tid]     + b1d[tid]);
        dw[dst+tid+64]  = f2b((x1-mean)*rstd*g1d[tid+64]  + b1d[tid+64]);
        dw[dst+tid+128] = f2b((x2-mean)*rstd*g1d[tid+128] + b1d[tid+128]);
    }
    cw[dst+tid]     = f2b(co[src+tid]);
    cw[dst+tid+64]  = f2b(co[src+tid+64]);
    cw[dst+tid+128] = f2b(co[src+tid+128]);
}

// ---------------------------------------------------------------------------
// Weight pre-convert: fp32 [K][N] -> bf16 MFMA-B-fragment order:
// dst[((kb*(N/16)+nig)*64 + lane)*8 + j] = W[kb*32 + 8*(lane>>4)+j][nig*16+(lane&15)]
// ---------------------------------------------------------------------------
__global__ __launch_bounds__(256)
void wconv(const float* w0,const float* w1,const float* w2,const float* w3,const float* w4,
           const float* w5,const float* w6,const float* w7,const float* w8, short* dst)
{
    const float* src; int K, N; long doff;
    switch (blockIdx.y) {
      case 0: src=w0; K=384; N=192; doff=0;      break;
      case 1: src=w1; K=384; N=192; doff=73728;  break;
      case 2: src=w2; K=192; N=384; doff=147456; break;
      case 3: src=w3; K=192; N=192; doff=221184; break;
      case 4: src=w4; K=192; N=192; doff=258048; break;
      case 5: src=w5; K=192; N=768; doff=294912; break;
      case 6: src=w6; K=768; N=192; doff=442368; break;
      case 7: src=w7; K=192; N=768; doff=589824; break;
      default:src=w8; K=768; N=192; doff=737280; break;
    }
    int nblk = (K>>5)*(N>>6);
    int bid = blockIdx.x;
    if (bid >= nblk) return;
    int kb = bid / (N>>6), nb = bid % (N>>6);
    __shared__ float tile[32][65];
    int tid = threadIdx.x;
    #pragma unroll
    for (int it = 0; it < 8; ++it) {
        int idx = tid + it*256;
        int r = idx >> 6, c = idx & 63;
        tile[r][c] = src[(long)(kb*32 + r)*N + nb*64 + c];
    }
    __syncthreads();
    int lane = tid & 63, nl = tid >> 6;
    short8 v;
    #pragma unroll
    for (int j = 0; j < 8; ++j)
        v[j] = f2bs(tile[(lane>>4)*8 + j][nl*16 + (lane&15)]);
    long nig = (long)nb*4 + nl;
    *(short8*)(dst + doff + (((long)kb*(N>>4) + nig)*64 + lane)*8) = v;
}

// ---------------------------------------------------------------------------
// fgemm: C[M x Nn] = A[M x K](bf16) @ Wfrag(bf16, frag-order) + bias(fp32)
// tile 64x192, 3 waves (wave-tile 64x64); A via 4KB frag-ordered LDS,
// B-frags DIRECT from global (L2-resident). MODEs as before.
// ---------------------------------------------------------------------------
template<int MODE>
__global__ __launch_bounds__(192)
void fgemm(const bf16* __restrict__ A1, const bf16* __restrict__ A2, int K1, int K,
           const short* __restrict__ wf, const float* __restrict__ bias, int Nn,
           bf16* __restrict__ out, bf16* __restrict__ out2,
           const float* __restrict__ res_src, const bf16* __restrict__ prj,
           int t0, float* __restrict__ dout)
{
    __shared__ short AsF[4][64][8];
    int tid = threadIdx.x;
    int wc = tid >> 6, lane = tid & 63;
    int l15 = lane & 15, g = lane >> 4;
    int row0 = blockIdx.x * 64, col0 = blockIdx.y * 192;
    const int ntiles = Nn >> 4;

    f32x4 acc[4][4];
    #pragma unroll
    for (int m = 0; m < 4; m++)
        #pragma unroll
        for (int n = 0; n < 4; n++)
            acc[m][n] = (f32x4){0.f,0.f,0.f,0.f};

    for (int k0 = 0; k0 < K; k0 += 32) {
        // stage A: 256 short8 chunks (row=c>>2, kseg=c&3), 192 threads
        {
            int c = tid;
            int row = c >> 2, kseg = c & 3;
            int col = k0 + kseg*8;
            const bf16* asrc = (col < K1) ? A1 : A2;
            int kc = (col < K1) ? col : col - K1;
            short8 av = *(const short8*)(asrc + (long)(row0+row)*K1 + kc);
            *((short8*)&AsF[row>>4][(row&15) + (kseg<<4)][0]) = av;
            if (tid < 64) {
                int c2 = 192 + tid;
                int row2 = c2 >> 2, ks2 = c2 & 3;
                int col2 = k0 + ks2*8;
                const bf16* as2 = (col2 < K1) ? A1 : A2;
                int kc2 = (col2 < K1) ? col2 : col2 - K1;
                short8 av2 = *(const short8*)(as2 + (long)(row0+row2)*K1 + kc2);
                *((short8*)&AsF[row2>>4][(row2&15) + (ks2<<4)][0]) = av2;
            }
        }
        __syncthreads();
        short8 af[4], bf4[4];
        #pragma unroll
        for (int m = 0; m < 4; m++) af[m] = *((short8*)&AsF[m][lane][0]);
        const short* wbase = wf + ((((long)(k0>>5))*ntiles + (col0>>4) + wc*4)*64 + lane)*8;
        #pragma unroll
        for (int n = 0; n < 4; n++) bf4[n] = *(const short8*)(wbase + ((long)n*64*8));
        #pragma unroll
        for (int m = 0; m < 4; m++)
            #pragma unroll
            for (int n = 0; n < 4; n++)
                acc[m][n] = __builtin_amdgcn_mfma_f32_16x16x32_bf16(af[m], bf4[n], acc[m][n], 0, 0, 0);
        __syncthreads();
    }

    // epilogue: D row = 16mi + 4g + rr, col = col0 + wc*64 + 16ni + l15
    #pragma unroll
    for (int m = 0; m < 4; m++) {
        #pragma unroll
        for (int rr = 0; rr < 4; rr++) {
            int t = row0 + m*16 + g*4 + rr;
            if (MODE == 4) {
                int tg = t0 + t;
                int b = tg / L_TOK, l = tg % L_TOK;
                int h = l / WW2, wcol = l % WW2;
                int hp = h - SS_;    if (hp < 0) hp += HH;
                int wp = wcol - SS_; if (wp < 0) wp += WW2;
                int b_ = b*NWIN + (hp/WS_)*8 + (wp/WS_);
                int n = (hp%WS_)*WS_ + (wp%WS_);
                long wsoff = ((long)b_*NW + n)*C_DIM;
                long goff  = (long)tg*C_DIM;
                #pragma unroll
                for (int n2 = 0; n2 < 4; n2++) {
                    int oc = col0 + wc*64 + n2*16 + l15;
                    float v = acc[m][n2][rr] + bias[oc];
                    dout[goff + oc] = res_src[goff + oc] + b2f(prj[wsoff + oc]) + v;
                }
            } else {
                #pragma unroll
                for (int n2 = 0; n2 < 4; n2++) {
                    int oc = col0 + wc*64 + n2*16 + l15;
                    float v = acc[m][n2][rr] + bias[oc];
                    if (MODE == 0) {
                        out[(long)t*Nn + oc] = f2b(v);
                    } else if (MODE == 1) {
                        int b_ = t / NW, n = t % NW;
                        if (oc < C_DIM) {
                            int head = oc >> 5, d = oc & 31;
                            out[(((long)b_*NH_ + head)*NW + n)*DH + d] = f2b(v * 0.17677669529663687f);
                        } else {
                            int och = oc - C_DIM;
                            int head = och >> 5, d = och & 31;
                            out2[(((long)b_*NH_ + head)*NW + n)*DH + d] = f2b(v);
                        }
                    } else if (MODE == 2) {
                        int b_ = t / NW, n = t % NW;
                        int head = oc >> 5, d = oc & 31;
                        out[(((long)b_*NH_ + head)*NW + n)*DH + d] = f2b(v);
                    } else { // MODE 3
                        float g2 = 0.5f * v * (1.0f + erff(v * 0.70710678118654752f));
                        out[(long)t*Nn + oc] = f2b(g2);
                    }
                }
            }
        }
    }
}

// ---------------------------------------------------------------------------
// mgemm (round-5 fallback, fp32 weights from global): 128x64 tile, 4 waves.
// ---------------------------------------------------------------------------
#define BM 128
#define BN 64

template<int MODE>
__global__ __launch_bounds__(256)
void mgemm(const bf16* __restrict__ A1, const bf16* __restrict__ A2, int K1, int K,
           const float* __restrict__ W, const float* __restrict__ bias, int Nn,
           bf16* __restrict__ out, bf16* __restrict__ out2,
           const float* __restrict__ res_src, const bf16* __restrict__ prj,
           int t0, float* __restrict__ dout)
{
    __shared__ short AsF[8][64][8];
    __shared__ short BsF[4][64][8];
    int tid  = threadIdx.x;
    int wid  = tid >> 6, lane = tid & 63;
    int wr   = wid >> 1, wc = wid & 1;
    int row0 = blockIdx.x * BM, col0 = blockIdx.y * BN;

    f32x4 acc[4][2];
    #pragma unroll
    for (int m = 0; m < 4; m++)
        #pragma unroll
        for (int n = 0; n < 2; n++)
            acc[m][n] = (f32x4){0.f, 0.f, 0.f, 0.f};

    int ar = tid >> 2, akseg = tid & 3;
    int bc = tid & 63, bk8 = tid >> 6;

    for (int k0 = 0; k0 < K; k0 += 32) {
        {
            int col = k0 + akseg*8;
            const bf16* asrc = (col < K1) ? A1 : A2;
            int akc = (col < K1) ? col : col - K1;
            #pragma unroll
            for (int rr = 0; rr < 2; rr++) {
                int r = ar + rr*64;
                short8 av = *(const short8*)(asrc + (long)(row0 + r)*K1 + akc);
                *((short8*)&AsF[r >> 4][(r & 15) + (akseg << 4)][0]) = av;
            }
        }
        {
            short8 bv;
            #pragma unroll
            for (int j = 0; j < 8; j++)
                bv[j] = f2bs(W[(long)(k0 + bk8*8 + j)*Nn + col0 + bc]);
            *((short8*)&BsF[bc >> 4][(bc & 15) + (bk8 << 4)][0]) = bv;
        }
        __syncthreads();
        short8 af[4], bfr[2];
        #pragma unroll
        for (int m = 0; m < 4; m++) af[m]  = *((short8*)&AsF[wr*4 + m][lane][0]);
        #pragma unroll
        for (int n = 0; n < 2; n++) bfr[n] = *((short8*)&BsF[wc*2 + n][lane][0]);
        #pragma unroll
        for (int m = 0; m < 4; m++)
            #pragma unroll
            for (int n = 0; n < 2; n++)
                acc[m][n] = __builtin_amdgcn_mfma_f32_16x16x32_bf16(af[m], bfr[n], acc[m][n], 0, 0, 0);
        __syncthreads();
    }

    #pragma unroll
    for (int m = 0; m < 4; m++) {
        #pragma unroll
        for (int rr = 0; rr < 4; rr++) {
            int t = row0 + wr*64 + m*16 + (lane >> 4)*4 + rr;
            if (MODE == 4) {
                int tg = t0 + t;
                int b = tg / L_TOK, l = tg % L_TOK;
                int h = l / WW2, wcol = l % WW2;
                int hp = h - SS_;    if (hp < 0) hp += HH;
                int wp = wcol - SS_; if (wp < 0) wp += WW2;
                int b_ = b*NWIN + (hp/WS_)*8 + (wp/WS_);
                int n  = (hp%WS_)*WS_ + (wp%WS_);
                long wsoff = ((long)b_*NW + n)*C_DIM;
                long goff  = (long)tg*C_DIM;
                #pragma unroll
                for (int n2 = 0; n2 < 2; n2++) {
                    int oc = col0 + wc*32 + n2*16 + (lane & 15);
                    float v = acc[m][n2][rr] + bias[oc];
                    dout[goff + oc] = res_src[goff + oc] + b2f(prj[wsoff + oc]) + v;
                }
            } else {
                #pragma unroll
                for (int n2 = 0; n2 < 2; n2++) {
                    int oc = col0 + wc*32 + n2*16 + (lane & 15);
                    float v = acc[m][n2][rr] + bias[oc];
                    if (MODE == 0) {
                        out[(long)t*Nn + oc] = f2b(v);
                    } else if (MODE == 1) {
                        int b_ = t / NW, n = t % NW;
                        if (oc < C_DIM) {
                            int head = oc >> 5, d = oc & 31;
                            out[(((long)b_*NH_ + head)*NW + n)*DH + d] = f2b(v * 0.17677669529663687f);
                        } else {
                            int och = oc - C_DIM;
                            int head = och >> 5, d = och & 31;
                            out2[(((long)b_*NH_ + head)*NW + n)*DH + d] = f2b(v);
                        }
                    } else if (MODE == 2) {
                        int b_ = t / NW, n = t % NW;
                        int head = oc >> 5, d = oc & 31;
                        out[(((long)b_*NH_ + head)*NW + n)*DH + d] = f2b(v);
                    } else {
                        float g2 = 0.5f * v * (1.0f + erff(v * 0.70710678118654752f));
                        out[(long)t*Nn + oc] = f2b(g2);
                    }
                }
            }
        }
    }
}

// ---------------------------------------------------------------------------
// MFMA attention: 1 wave per (window,head), 2 waves/block.
// QK^T (16 mfma) -> bias(LDS table)+computed shift-mask -> D-layout softmax
// -> P via LDS -> PV (32 mfma, both streams). Mask computed from geometry.
// ---------------------------------------------------------------------------
#define PSTR 72
#define VSTR 72

__global__ __launch_bounds__(128)
void attn_mfma(const bf16* __restrict__ qb, const bf16* __restrict__ kb,
               const bf16* __restrict__ vse, const bf16* __restrict__ vde,
               const float* __restrict__ rpb,
               bf16* __restrict__ ose, bf16* __restrict__ ode)
{
    __shared__ float rpbs[169*NH_];
    __shared__ short P[2][64][PSTR];
    __shared__ short VTs[2][32][VSTR];
    __shared__ short VTd[2][32][VSTR];
    int tid = threadIdx.x, wid = tid >> 6, lane = tid & 63;
    for (int i = tid; i < 169*NH_; i += 128) rpbs[i] = rpb[i];
    __syncthreads();

    int bh = blockIdx.x*2 + wid;
    int b_ = bh / NH_, head = bh % NH_;
    int w = b_ & (NWIN-1);
    int wh = w >> 3, ww = w & 7;
    long base = (long)bh * (NW*DH);
    int l15 = lane & 15, g = lane >> 4;

    // --- Q/K fragments direct from global (rows clamped into valid range)
    short8 qf[4], kf[4];
    #pragma unroll
    for (int mi = 0; mi < 4; mi++) {
        int r = l15 + 16*mi; if (r > 48) r = 48;
        qf[mi] = *(const short8*)(qb + base + r*DH + 8*g);
    }
    #pragma unroll
    for (int ni = 0; ni < 4; ni++) {
        int r = l15 + 16*ni; if (r > 48) r = 48;
        kf[ni] = *(const short8*)(kb + base + r*DH + 8*g);
    }

    // --- QK^T: S[64][64], D-layout (col=l15+16ni, row=16mi+4g+rr)
    f32x4 sA[4][4];
    #pragma unroll
    for (int mi = 0; mi < 4; mi++)
        #pragma unroll
        for (int ni = 0; ni < 4; ni++)
            sA[mi][ni] = (f32x4){0.f,0.f,0.f,0.f};
    #pragma unroll
    for (int mi = 0; mi < 4; mi++)
        #pragma unroll
        for (int ni = 0; ni < 4; ni++)
            sA[mi][ni] = __builtin_amdgcn_mfma_f32_16x16x32_bf16(qf[mi], kf[ni], sA[mi][ni], 0, 0, 0);

    // --- stage V transposed (both streams): VT[d][j], zeros for j>=49
    {
        int j0 = lane >> 2, seg = lane & 3;
        #pragma unroll
        for (int it = 0; it < 4; ++it) {
            int j = j0 + 16*it;
            short8 a = {0,0,0,0,0,0,0,0}, bv = {0,0,0,0,0,0,0,0};
            if (j < NW) {
                a  = *(const short8*)(vse + base + j*DH + seg*8);
                bv = *(const short8*)(vde + base + j*DH + seg*8);
            }
            #pragma unroll
            for (int s2 = 0; s2 < 8; ++s2) {
                VTs[wid][seg*8 + s2][j] = a[s2];
                VTd[wid][seg*8 + s2][j] = bv[s2];
            }
        }
    }

    // --- per-lane column-side geometry (j = 16ni + l15)
    int jv[4], j7r_[4], j7c_[4], jrh_[4], jrc_[4];
    #pragma unroll
    for (int ni = 0; ni < 4; ++ni) {
        int j = 16*ni + l15;
        jv[ni] = (j < NW);
        int a = (j*37) >> 8; int c = j - 7*a;
        j7r_[ni] = a; j7c_[ni] = c;
        int jh = wh*7 + a, jw = ww*7 + c;
        jrh_[ni] = (jh >= 49) + (jh >= 53);
        jrc_[ni] = (jw >= 49) + (jw >= 53);
    }

    // --- bias + mask + softmax (row-wise over j), write P (bf16) to LDS
    #pragma unroll
    for (int mi = 0; mi < 4; mi++) {
        #pragma unroll
        for (int rr = 0; rr < 4; rr++) {
            int i = 16*mi + 4*g + rr;
            int iv = (i < NW);
            int i7r = (i*37) >> 8; int i7c = i - 7*i7r;
            int ih = wh*7 + i7r, iw = ww*7 + i7c;
            int irh = (ih >= 49) + (ih >= 53), irc = (iw >= 49) + (iw >= 53);
            float sv[4];
            #pragma unroll
            for (int ni = 0; ni < 4; ni++) {
                if (iv && jv[ni]) {
                    int ri = (i7r - j7r_[ni] + 6)*13 + (i7c - j7c_[ni] + 6);
                    float msk = (irh == jrh_[ni] && irc == jrc_[ni]) ? 0.f : -100.f;
                    sv[ni] = sA[mi][ni][rr] + rpbs[ri*NH_ + head] + msk;
                } else {
                    sv[ni] = -1e30f;
                }
            }
            float mx = fmaxf(fmaxf(sv[0], sv[1]), fmaxf(sv[2], sv[3]));
            mx = fmaxf(mx, __shfl_xor(mx, 1));
            mx = fmaxf(mx, __shfl_xor(mx, 2));
            mx = fmaxf(mx, __shfl_xor(mx, 4));
            mx = fmaxf(mx, __shfl_xor(mx, 8));
            float e[4], sum = 0.f;
            #pragma unroll
            for (int ni = 0; ni < 4; ni++) { e[ni] = __expf(sv[ni] - mx); sum += e[ni]; }
            sum += __shfl_xor(sum, 1);
            sum += __shfl_xor(sum, 2);
            sum += __shfl_xor(sum, 4);
            sum += __shfl_xor(sum, 8);
            float inv = 1.0f / sum;
            #pragma unroll
            for (int ni = 0; ni < 4; ni++)
                P[wid][i][16*ni + l15] = f2bs(e[ni] * inv);
        }
    }
    __syncthreads();

    // --- PV for both streams: O[i][d] = sum_j P[i][j] * V[j][d]
    f32x4 o1[4][2], o2[4][2];
    #pragma unroll
    for (int mi = 0; mi < 4; mi++)
        #pragma unroll
        for (int di = 0; di < 2; di++) {
            o1[mi][di] = (f32x4){0.f,0.f,0.f,0.f};
            o2[mi][di] = (f32x4){0.f,0.f,0.f,0.f};
        }
    #pragma unroll
    for (int mi = 0; mi < 4; mi++) {
        #pragma unroll
        for (int kk = 0; kk < 2; kk++) {
            short8 ap = *((short8*)&P[wid][16*mi + l15][kk*32 + 8*g]);
            #pragma unroll
            for (int di = 0; di < 2; di++) {
                short8 bv1 = *((short8*)&VTs[wid][16*di + l15][kk*32 + 8*g]);
                o1[mi][di] = __builtin_amdgcn_mfma_f32_16x16x32_bf16(ap, bv1, o1[mi][di], 0, 0, 0);
                short8 bv2 = *((short8*)&VTd[wid][16*di + l15][kk*32 + 8*g]);
                o2[mi][di] = __builtin_amdgcn_mfma_f32_16x16x32_bf16(ap, bv2, o2[mi][di], 0, 0, 0);
            }
        }
    }

    // --- epilogue: write valid rows
    #pragma unroll
    for (int mi = 0; mi < 4; mi++) {
        #pragma unroll
        for (int rr = 0; rr < 4; rr++) {
            int i = 16*mi + 4*g + rr;
            if (i < NW) {
                long ob = ((long)b_*NW + i)*C_DIM + head*DH;
                #pragma unroll
                for (int di = 0; di < 2; di++) {
                    ose[ob + 16*di + l15] = f2b(o1[mi][di][rr]);
                    ode[ob + 16*di + l15] = f2b(o2[mi][di][rr]);
                }
            }
        }
    }
}

// ---------------------------------------------------------------------------
// Fused window-reverse + un-shift + residual + LN2 (xn only).
// ---------------------------------------------------------------------------
__global__ void resid_ln2_kernel(const float* __restrict__ se, const float* __restrict__ de,
                                 const bf16* __restrict__ pse, const bf16* __restrict__ pde,
                                 const float* __restrict__ g2s, const float* __restrict__ bb2s,
                                 const float* __restrict__ g2d, const float* __restrict__ bb2d,
                                 bf16* __restrict__ xns, bf16* __restrict__ xnd)
{
    int t = blockIdx.x, tid = threadIdx.x;
    int b = t / L_TOK, l = t % L_TOK;
    int h = l / WW2, wc = l % WW2;
    int hp = h - SS_;  if (hp < 0) hp += HH;
    int wp = wc - SS_; if (wp < 0) wp += WW2;
    int b_ = b*NWIN + (hp/WS_)*8 + (wp/WS_);
    int n  = (hp%WS_)*WS_ + (wp%WS_);
    long wsoff = ((long)b_*NW + n)*C_DIM;
    long off   = (long)t*C_DIM;
    {
        float x0 = se[off+tid]     + b2f(pse[wsoff+tid]);
        float x1 = se[off+tid+64]  + b2f(pse[wsoff+tid+64]);
        float x2 = se[off+tid+128] + b2f(pse[wsoff+tid+128]);
        float s  = wave_sum64(x0+x1+x2);
        float ss = wave_sum64(x0*x0 + x1*x1 + x2*x2);
        float mean = s * (1.0f/192.0f);
        float var  = ss * (1.0f/192.0f) - mean*mean;
        float rstd = rsqrtf(var + 1e-5f);
        xns[off+tid]     = f2b((x0-mean)*rstd*g2s[tid]     + bb2s[tid]);
        xns[off+tid+64]  = f2b((x1-mean)*rstd*g2s[tid+64]  + bb2s[tid+64]);
        xns[off+tid+128] = f2b((x2-mean)*rstd*g2s[tid+128] + bb2s[tid+128]);
    }
    {
        float x0 = de[off+tid]     + b2f(pde[wsoff+tid]);
        float x1 = de[off+tid+64]  + b2f(pde[wsoff+tid+64]);
        float x2 = de[off+tid+128] + b2f(pde[wsoff+tid+128]);
        float s  = wave_sum64(x0+x1+x2);
        float ss = wave_sum64(x0*x0 + x1*x1 + x2*x2);
        float mean = s * (1.0f/192.0f);
        float var  = ss * (1.0f/192.0f) - mean*mean;
        float rstd = rsqrtf(var + 1e-5f);
        xnd[off+tid]     = f2b((x0-mean)*rstd*g2d[tid]     + bb2d[tid]);
        xnd[off+tid+64]  = f2b((x1-mean)*rstd*g2d[tid+64]  + bb2d[tid+64]);
        xnd[off+tid+128] = f2b((x2-mean)*rstd*g2d[tid+128] + bb2d[tid+128]);
    }
}

// ---------------------------------------------------------------------------
extern "C" void kernel_launch(void* const* d_in, const int* in_sizes, int n_in,
                              void* d_out, int out_size, void* d_ws, size_t ws_size,
                              hipStream_t stream)
{
    const float* se     = (const float*)d_in[0];
    const float* de     = (const float*)d_in[1];
    const float* co     = (const float*)d_in[2];
    const float* n1se_g = (const float*)d_in[4];
    const float* n1se_b = (const float*)d_in[5];
    const float* n1de_g = (const float*)d_in[6];
    const float* n1de_b = (const float*)d_in[7];
    const float* rpb    = (const float*)d_in[8];
    const float* vse_w  = (const float*)d_in[9];
    const float* vse_b  = (const float*)d_in[10];
    const float* vde_w  = (const float*)d_in[11];
    const float* vde_b  = (const float*)d_in[12];
    const float* qk_w   = (const float*)d_in[13];
    const float* qk_b   = (const float*)d_in[14];
    const float* pse_w  = (const float*)d_in[15];
    const float* pse_b  = (const float*)d_in[16];
    const float* pde_w  = (const float*)d_in[17];
    const float* pde_b  = (const float*)d_in[18];
    const float* n2se_g = (const float*)d_in[19];
    const float* n2se_b = (const float*)d_in[20];
    const float* n2de_g = (const float*)d_in[21];
    const float* n2de_b = (const float*)d_in[22];
    const float* mse_w1 = (const float*)d_in[23];
    const float* mse_b1 = (const float*)d_in[24];
    const float* mse_w2 = (const float*)d_in[25];
    const float* mse_b2 = (const float*)d_in[26];
    const float* mde_w1 = (const float*)d_in[27];
    const float* mde_b1 = (const float*)d_in[28];
    const float* mde_w2 = (const float*)d_in[29];
    const float* mde_b2 = (const float*)d_in[30];

    char* ws = (char*)d_ws;
    const size_t U = (size_t)TOK * C_DIM * 2;   // 19,267,584 bytes
    bf16* sw  = (bf16*)(ws + 0*U);
    bf16* dw  = (bf16*)(ws + 1*U);
    bf16* cw  = (bf16*)(ws + 2*U);
    bf16* vse = (bf16*)(ws + 3*U);
    bf16* vde = (bf16*)(ws + 4*U);
    bf16* ode = (bf16*)(ws + 5*U);
    bf16* qb  = (bf16*)(ws + 0*U);
    bf16* kb  = (bf16*)(ws + 1*U);
    bf16* ose = (bf16*)(ws + 2*U);
    bf16* pse = (bf16*)(ws + 0*U);
    bf16* pde = (bf16*)(ws + 1*U);
    bf16* xns = (bf16*)(ws + 2*U);
    bf16* xnd = (bf16*)(ws + 3*U);
    bf16* hid = (bf16*)(ws + 4*U);
    short* wfb = (short*)(ws + 6*U);            // 884,736 bf16 = 1.73 MB

    const bool frag = (ws_size >= 6*U + 884736ull*2ull);
    float* dout = (float*)d_out;
    const int CH = TOK/2;

    if (frag)
        wconv<<<dim3(72, 9), 256, 0, stream>>>(vse_w, vde_w, qk_w, pse_w, pde_w,
                                               mse_w1, mse_w2, mde_w1, mde_w2, wfb);
    prep_kernel<<<TOK, 64, 0, stream>>>(se, de, co, n1se_g, n1se_b, n1de_g, n1de_b, sw, dw, cw);

    if (frag) {
        fgemm<2><<<dim3(TOK/64, 1), 192, 0, stream>>>(sw, cw, C_DIM, 2*C_DIM, wfb + 0,      vse_b, C_DIM,
                                                      vse, nullptr, nullptr, nullptr, 0, nullptr);
        fgemm<2><<<dim3(TOK/64, 1), 192, 0, stream>>>(dw, cw, C_DIM, 2*C_DIM, wfb + 73728,  vde_b, C_DIM,
                                                      vde, nullptr, nullptr, nullptr, 0, nullptr);
        fgemm<1><<<dim3(TOK/64, 2), 192, 0, stream>>>(cw, cw, C_DIM, C_DIM,   wfb + 147456, qk_b, 384,
                                                      qb, kb, nullptr, nullptr, 0, nullptr);
    } else {
        mgemm<2><<<dim3(TOK/BM, C_DIM/BN), 256, 0, stream>>>(sw, cw, C_DIM, 2*C_DIM, vse_w, vse_b, C_DIM,
                                                             vse, nullptr, nullptr, nullptr, 0, nullptr);
        mgemm<2><<<dim3(TOK/BM, C_DIM/BN), 256, 0, stream>>>(dw, cw, C_DIM, 2*C_DIM, vde_w, vde_b, C_DIM,
                                                             vde, nullptr, nullptr, nullptr, 0, nullptr);
        mgemm<1><<<dim3(TOK/BM, 384/BN), 256, 0, stream>>>(cw, cw, C_DIM, C_DIM, qk_w, qk_b, 384,
                                                           qb, kb, nullptr, nullptr, 0, nullptr);
    }

    attn_mfma<<<BWIN*NH_/2, 128, 0, stream>>>(qb, kb, vse, vde, rpb, ose, ode);

    if (frag) {
        fgemm<0><<<dim3(TOK/64, 1), 192, 0, stream>>>(ose, ose, C_DIM, C_DIM, wfb + 221184, pse_b, C_DIM,
                                                      pse, nullptr, nullptr, nullptr, 0, nullptr);
        fgemm<0><<<dim3(TOK/64, 1), 192, 0, stream>>>(ode, ode, C_DIM, C_DIM, wfb + 258048, pde_b, C_DIM,
                                                      pde, nullptr, nullptr, nullptr, 0, nullptr);
    } else {
        mgemm<0><<<dim3(TOK/BM, C_DIM/BN), 256, 0, stream>>>(ose, ose, C_DIM, C_DIM, pse_w, pse_b, C_DIM,
                                                             pse, nullptr, nullptr, nullptr, 0, nullptr);
        mgemm<0><<<dim3(TOK/BM, C_DIM/BN), 256, 0, stream>>>(ode, ode, C_DIM, C_DIM, pde_w, pde_b, C_DIM,
                                                             pde, nullptr, nullptr, nullptr, 0, nullptr);
    }

    resid_ln2_kernel<<<TOK, 64, 0, stream>>>(se, de, pse, pde,
                                             n2se_g, n2se_b, n2de_g, n2de_b, xns, xnd);

    if (frag) {
        for (int c0 = 0; c0 < 2; c0++) {
            int t0 = c0 * CH;
            fgemm<3><<<dim3(CH/64, 4), 192, 0, stream>>>(xns + (long)t0*C_DIM, xns + (long)t0*C_DIM,
                                                         C_DIM, C_DIM, wfb + 294912, mse_b1, HID_,
                                                         hid, nullptr, nullptr, nullptr, 0, nullptr);
            fgemm<4><<<dim3(CH/64, 1), 192, 0, stream>>>(hid, hid, HID_, HID_, wfb + 442368, mse_b2, C_DIM,
                                                         nullptr, nullptr, se, pse, t0, dout);
        }
        for (int c0 = 0; c0 < 2; c0++) {
            int t0 = c0 * CH;
            fgemm<3><<<dim3(CH/64, 4), 192, 0, stream>>>(xnd + (long)t0*C_DIM, xnd + (long)t0*C_DIM,
                                                         C_DIM, C_DIM, wfb + 589824, mde_b1, HID_,
                                                         hid, nullptr, nullptr, nullptr, 0, nullptr);
            fgemm<4><<<dim3(CH/64, 1), 192, 0, stream>>>(hid, hid, HID_, HID_, wfb + 737280, mde_b2, C_DIM,
                                                         nullptr, nullptr, de, pde, t0,
                                                         dout + (size_t)TOK*C_DIM);
        }
    } else {
        for (int c0 = 0; c0 < 2; c0++) {
            int t0 = c0 * CH;
            mgemm<3><<<dim3(CH/BM, HID_/BN), 256, 0, stream>>>(xns + (long)t0*C_DIM, xns + (long)t0*C_DIM,
                                                               C_DIM, C_DIM, mse_w1, mse_b1, HID_,
                                                               hid, nullptr, nullptr, nullptr, 0, nullptr);
            mgemm<4><<<dim3(CH/BM, C_DIM/BN), 256, 0, stream>>>(hid, hid, HID_, HID_, mse_w2, mse_b2, C_DIM,
                                                                nullptr, nullptr, se, pse, t0, dout);
        }
        for (int c0 = 0; c0 < 2; c0++) {
            int t0 = c0 * CH;
            mgemm<3><<<dim3(CH/BM, HID_/BN), 256, 0, stream>>>(xnd + (long)t0*C_DIM, xnd + (long)t0*C_DIM,
                                                               C_DIM, C_DIM, mde_w1, mde_b1, HID_,
                                                               hid, nullptr, nullptr, nullptr, 0, nullptr);
            mgemm<4><<<dim3(CH/BM, C_DIM/BN), 256, 0, stream>>>(hid, hid, HID_, HID_, mde_w2, mde_b2, C_DIM,
                                                                nullptr, nullptr, de, pde, t0,
                                                                dout + (size_t)TOK*C_DIM);
        }
    }
}